// Round 16
// baseline (216.501 us; speedup 1.0000x reference)
//
#include <hip/hip_runtime.h>

#define C 64
#define NBLK 512      // partition blocks for count/scatter passes
#define RN 256        // nodes per bin (pow2: bin = dst>>8, local = dst&255)
#define CAP 6144      // per-bin LDS edge capacity (mean 4096, +32 sigma)

typedef __attribute__((ext_vector_type(8))) short bf16x8;
typedef __attribute__((ext_vector_type(4))) float f32x4;

// round-to-nearest-even f32 -> bf16 bits
__device__ __forceinline__ short f2bf(float f) {
    union { float f; unsigned u; } v; v.f = f;
    unsigned r = v.u + 0x7fff + ((v.u >> 16) & 1);
    return (short)(r >> 16);
}

__device__ __forceinline__ float bf2f(short s) {
    union { unsigned u; float f; } v;
    v.u = ((unsigned)(unsigned short)s) << 16;
    return v.f;
}

__device__ __forceinline__ bf16x8 cvt8(const float* __restrict__ p, float scale) {
    bf16x8 r;
#pragma unroll
    for (int i = 0; i < 8; ++i) r[i] = f2bf(p[i] * scale);
    return r;
}

// Mrow[o*64+j] = sum_i linr_w[o][i] * lin_w[i][j]; bc[o] = linr_w[o]·lin_b
__global__ void precompute_wb(const float* __restrict__ lin_w,
                              const float* __restrict__ lin_b,
                              const float* __restrict__ linr_w,
                              float* __restrict__ Mrow,
                              float* __restrict__ bc) {
    int o = blockIdx.x;
    int j = threadIdx.x;
    float acc = 0.f;
#pragma unroll
    for (int i = 0; i < C; ++i)
        acc += linr_w[o * C + i] * lin_w[i * C + j];
    Mrow[o * C + j] = acc;
    if (j == 0) {
        float b = 0.f;
#pragma unroll
        for (int i = 0; i < C; ++i) b += linr_w[o * C + i] * lin_b[i];
        bc[o] = b;
    }
}

// x (f32) -> xb (bf16): halves gather traffic; also feeds matmul A-frags directly.
__global__ __launch_bounds__(256) void cvt_x(const float* __restrict__ x,
                                             bf16x8* __restrict__ xb, int nchunk) {
    int stride = gridDim.x * blockDim.x;
    for (int i = blockIdx.x * blockDim.x + threadIdx.x; i < nchunk; i += stride)
        xb[i] = cvt8(x + (size_t)i * 8, 1.0f);
}

// Pass 1a: per-(block,bin) edge counts via LDS histogram. counts[bin*NBLK + b].
__global__ __launch_bounds__(256) void count_bins(const int* __restrict__ ei,
                                                  int* __restrict__ counts,
                                                  int E, int nsup) {
    __shared__ int bins[1024];
    int t = threadIdx.x, b = blockIdx.x;
    for (int i = t; i < nsup; i += 256) bins[i] = 0;
    __syncthreads();
    int epb = (E + NBLK - 1) / NBLK;
    int e0 = b * epb, e1 = min(E, e0 + epb);
    for (int e = e0 + t; e < e1; e += 256)
        atomicAdd(&bins[ei[E + e] >> 8], 1);
    __syncthreads();
    for (int i = t; i < nsup; i += 256) counts[i * NBLK + b] = bins[i];
}

// Pass 1b: bin totals
__global__ __launch_bounds__(256) void sum_bins(const int* __restrict__ counts,
                                                int* __restrict__ rtot) {
    int r = blockIdx.x, t = threadIdx.x;
    const int* row = counts + (size_t)r * NBLK;
    int s = 0;
    for (int i = t; i < NBLK; i += 256) s += row[i];
    __shared__ int red[256];
    red[t] = s;
    __syncthreads();
    for (int o = 128; o > 0; o >>= 1) {
        if (t < o) red[t] += red[t + o];
        __syncthreads();
    }
    if (t == 0) rtot[r] = red[0];
}

// Pass 1c: exclusive scan of bin totals (nsup <= 512), single block
__global__ __launch_bounds__(512) void scan_tot(const int* __restrict__ rtot,
                                                int* __restrict__ rstart, int nsup) {
    __shared__ int tmp[512];
    int t = threadIdx.x;
    int v = t < nsup ? rtot[t] : 0;
    tmp[t] = v;
    __syncthreads();
    for (int o = 1; o < 512; o <<= 1) {
        int u = (t >= o) ? tmp[t - o] : 0;
        __syncthreads();
        tmp[t] += u;
        __syncthreads();
    }
    if (t < nsup) rstart[t] = tmp[t] - v;
}

// Pass 1d: per-bin scan over blocks -> absolute cursors, in-place into counts
__global__ __launch_bounds__(512) void scan_bins(int* __restrict__ counts,
                                                 const int* __restrict__ rstart) {
    int r = blockIdx.x, t = threadIdx.x;
    int* row = counts + (size_t)r * NBLK;
    __shared__ int tmp[512];
    int v = t < NBLK ? row[t] : 0;
    tmp[t] = v;
    __syncthreads();
    for (int o = 1; o < 512; o <<= 1) {
        int u = (t >= o) ? tmp[t - o] : 0;
        __syncthreads();
        tmp[t] += u;
        __syncthreads();
    }
    if (t < NBLK) row[t] = rstart[r] + tmp[t] - v;
}

// Pass 2: scatter packed (src<<8 | dst&255) into bin-contiguous pairs[].
// Cursors in LDS; each (block,bin) run is consecutive & time-local -> no write amp.
__global__ __launch_bounds__(256) void scatter_pairs(const int* __restrict__ ei,
                                                     const int* __restrict__ counts,
                                                     int* __restrict__ pairs,
                                                     int E, int nsup) {
    __shared__ int cur[1024];
    int t = threadIdx.x, b = blockIdx.x;
    for (int i = t; i < nsup; i += 256) cur[i] = counts[(size_t)i * NBLK + b];
    __syncthreads();
    int epb = (E + NBLK - 1) / NBLK;
    int e0 = b * epb, e1 = min(E, e0 + epb);
    for (int e = e0 + t; e < e1; e += 256) {
        int s = ei[e], d = ei[E + e];
        int pos = atomicAdd(&cur[d >> 8], 1);
        pairs[pos] = (s << 8) | (d & 255);
    }
}

// Pass 3: fused per-bin sort + gather (bf16 rows: 128B, 8 lanes x 16B).
// One block per bin (256 nodes), 1024 thr. Writes f32 agg (into d_out) + cnt.
__global__ __launch_bounds__(1024) void gather_fused(const bf16x8* __restrict__ xb,
                                                     const int* __restrict__ pairs,
                                                     const int* __restrict__ rstart,
                                                     const int* __restrict__ rtot,
                                                     int* __restrict__ cnt,
                                                     float* __restrict__ agg, int N) {
    __shared__ int cntl[256], starts[256], cur[256], tmp[256];
    __shared__ int sorted[CAP];
    int t = threadIdx.x, r = blockIdx.x;
    int lo = r << 8;
    int base = rstart[r];
    int ne = min(rtot[r], CAP);

    if (t < 256) cntl[t] = 0;
    __syncthreads();
    for (int i = t; i < ne; i += 1024)
        atomicAdd(&cntl[pairs[base + i] & 255], 1);
    __syncthreads();
    if (t < 256) tmp[t] = cntl[t];
    __syncthreads();
    for (int o = 1; o < 256; o <<= 1) {
        int u = (t < 256 && t >= o) ? tmp[t - o] : 0;
        __syncthreads();
        if (t < 256) tmp[t] += u;
        __syncthreads();
    }
    if (t < 256) {
        starts[t] = tmp[t] - cntl[t];
        cur[t] = starts[t];
    }
    __syncthreads();
    for (int i = t; i < ne; i += 1024) {
        int p = pairs[base + i];
        int pos = atomicAdd(&cur[p & 255], 1);
        sorted[pos] = p >> 8;
    }
    __syncthreads();
    // gather: 8 groups of 8 lanes; group g handles edge i+g, lane reads 16B chunk li2
    int wv = t >> 6, lane = t & 63, g = lane >> 3, li2 = lane & 7;
    for (int l = wv; l < 256; l += 16) {
        int n = lo + l;
        if (n >= N) break;
        int s0 = starts[l], deg = cntl[l];
        float a[8] = {0, 0, 0, 0, 0, 0, 0, 0}, b2[8] = {0, 0, 0, 0, 0, 0, 0, 0};
        int i = 0;
        for (; i + 16 <= deg; i += 16) {
            int sA = sorted[s0 + i + g];
            int sB = sorted[s0 + i + 8 + g];
            bf16x8 vA = xb[(size_t)sA * 8 + li2];
            bf16x8 vB = xb[(size_t)sB * 8 + li2];
#pragma unroll
            for (int k = 0; k < 8; ++k) { a[k] += bf2f(vA[k]); b2[k] += bf2f(vB[k]); }
        }
        for (; i + 8 <= deg; i += 8) {
            int sA = sorted[s0 + i + g];
            bf16x8 vA = xb[(size_t)sA * 8 + li2];
#pragma unroll
            for (int k = 0; k < 8; ++k) a[k] += bf2f(vA[k]);
        }
        if (i < deg) {
            int idx = i + g;
            int sA = sorted[s0 + min(idx, deg - 1)];
            float w = idx < deg ? 1.f : 0.f;
            bf16x8 vA = xb[(size_t)sA * 8 + li2];
#pragma unroll
            for (int k = 0; k < 8; ++k) a[k] = fmaf(w, bf2f(vA[k]), a[k]);
        }
#pragma unroll
        for (int k = 0; k < 8; ++k) {
            a[k] += b2[k];
            a[k] += __shfl_xor(a[k], 8);
            a[k] += __shfl_xor(a[k], 16);
            a[k] += __shfl_xor(a[k], 32);
        }
        if (g == 0) {
            float4 r1, r2;
            r1.x = a[0]; r1.y = a[1]; r1.z = a[2]; r1.w = a[3];
            r2.x = a[4]; r2.y = a[5]; r2.z = a[6]; r2.w = a[7];
            float* dst = agg + (size_t)n * C + li2 * 8;
            *(float4*)dst = r1;
            *(float4*)(dst + 4) = r2;
        }
        if (lane == 0) cnt[n] = deg;
    }
}

// MFMA matmul: out[N][64] = [xb | bf16(agg*inv)] @ bf16(Wcat^T) + bl + ind*bc
// A-frags for x read directly from the bf16 table (bit reinterpret, no cvt).
// agg aliases out: wave reads its 16 rows into fragments before storing them.
__global__ __launch_bounds__(256) void matmul_mfma(const bf16x8* __restrict__ xb,
                                                   const float* agg,
                                                   const int* __restrict__ cnt,
                                                   const float* __restrict__ linl_w,
                                                   const float* __restrict__ linl_b,
                                                   const float* __restrict__ Mrow,
                                                   const float* __restrict__ bc,
                                                   float* out, int N) {
    int t = threadIdx.x;
    int wv = t >> 6, lane = t & 63;
    int lrow = lane & 15;
    int kblk = lane >> 4;
    int koff = kblk * 8;

    bf16x8 Bf[4][4];
#pragma unroll
    for (int c = 0; c < 4; ++c) {
        int o = c * 16 + lrow;
#pragma unroll
        for (int q = 0; q < 4; ++q) {
            const float* src = (q < 2) ? (linl_w + (size_t)o * C + q * 32 + koff)
                                       : (Mrow + (size_t)o * C + (q - 2) * 32 + koff);
            Bf[c][q] = cvt8(src, 1.0f);
        }
    }
    float blv[4], bcv[4];
#pragma unroll
    for (int c = 0; c < 4; ++c) {
        blv[c] = linl_b[c * 16 + lrow];
        bcv[c] = bc[c * 16 + lrow];
    }

    int ntiles = (N + 15) >> 4;
    int nw = gridDim.x * 4;
    for (int tile = blockIdx.x * 4 + wv; tile < ntiles; tile += nw) {
        int n0 = tile * 16;
        int ar = min(n0 + lrow, N - 1);
        float inva = 1.0f / (float)max(cnt[ar], 1);
        const float* gr = agg + (size_t)ar * C;
        bf16x8 Af[4];
        Af[0] = xb[(size_t)ar * 8 + kblk];       // x, k = koff..koff+7
        Af[1] = xb[(size_t)ar * 8 + 4 + kblk];   // x, k = 32+koff..
        Af[2] = cvt8(gr + koff, inva);
        Af[3] = cvt8(gr + 32 + koff, inva);

        f32x4 acc[4] = {{0, 0, 0, 0}, {0, 0, 0, 0}, {0, 0, 0, 0}, {0, 0, 0, 0}};
#pragma unroll
        for (int q = 0; q < 4; ++q)
#pragma unroll
            for (int c = 0; c < 4; ++c)
                acc[c] = __builtin_amdgcn_mfma_f32_16x16x32_bf16(Af[q], Bf[c][q],
                                                                 acc[c], 0, 0, 0);

#pragma unroll
        for (int r = 0; r < 4; ++r) {
            int nrow = n0 + kblk * 4 + r;
            if (nrow < N) {
                float ind = cnt[nrow] > 0 ? 1.f : 0.f;
#pragma unroll
                for (int c = 0; c < 4; ++c)
                    out[(size_t)nrow * C + c * 16 + lrow] =
                        acc[c][r] + blv[c] + ind * bcv[c];
            }
        }
    }
}

extern "C" void kernel_launch(void* const* d_in, const int* in_sizes, int n_in,
                              void* d_out, int out_size, void* d_ws, size_t ws_size,
                              hipStream_t stream) {
    const float* x      = (const float*)d_in[0];
    const int*   ei     = (const int*)d_in[1];
    const float* lin_w  = (const float*)d_in[2];
    const float* lin_b  = (const float*)d_in[3];
    const float* linl_w = (const float*)d_in[4];
    const float* linl_b = (const float*)d_in[5];
    const float* linr_w = (const float*)d_in[6];

    int N = in_sizes[0] / C;
    int E = in_sizes[1] / 2;
    int nsup = (N + RN - 1) / RN;   // 391 bins for N=100000

    // ws layout (4B units):
    // counts[nsup*NBLK] | rtot | rstart | cnt[N] | pairs[E] | Mrow[4096] | bc[64] | xb[N*32 (16B-aligned)]
    int* counts = (int*)d_ws;
    int* rtot   = counts + (size_t)nsup * NBLK;
    int* rstart = rtot + nsup;
    int* cnt    = rstart + nsup;
    int* pairs  = cnt + N;
    float* Mrow = (float*)(pairs + E);
    float* bc   = Mrow + C * C;
    uintptr_t xaddr = ((uintptr_t)(bc + C) + 15) & ~(uintptr_t)15;
    bf16x8* xb = (bf16x8*)xaddr;

    float* agg = (float*)d_out;  // neighbor sums land in d_out, then matmul in-place

    precompute_wb<<<C, C, 0, stream>>>(lin_w, lin_b, linr_w, Mrow, bc);

    cvt_x<<<2048, 256, 0, stream>>>(x, xb, N * 8);

    count_bins<<<NBLK, 256, 0, stream>>>(ei, counts, E, nsup);
    sum_bins<<<nsup, 256, 0, stream>>>(counts, rtot);
    scan_tot<<<1, 512, 0, stream>>>(rtot, rstart, nsup);
    scan_bins<<<nsup, 512, 0, stream>>>(counts, rstart);
    scatter_pairs<<<NBLK, 256, 0, stream>>>(ei, counts, pairs, E, nsup);

    gather_fused<<<nsup, 1024, 0, stream>>>(xb, pairs, rstart, rtot, cnt, agg, N);

    int ntiles = (N + 15) / 16;
    int mblocks = (ntiles + 3) / 4;
    if (mblocks > 2048) mblocks = 2048;
    matmul_mfma<<<mblocks, 256, 0, stream>>>(xb, agg, cnt, linl_w, linl_b, Mrow, bc,
                                             (float*)d_out, N);
}